// Round 1
// baseline (1770.778 us; speedup 1.0000x reference)
//
#include <hip/hip_runtime.h>
#include <math.h>

#define LSZ 128
#define NCH 8
#define NLAY 16

// One block per (batch, channel) plane. 512 threads: 16 row-strips x 32 col-groups.
// Each thread owns an 8-row x 4-col tile. x plane lives in LDS (64KB), updated
// in place each layer: compute results into registers, barrier, store, barrier.
__global__ __launch_bounds__(512, 4) void plane_kernel(
    const float* __restrict__ nrm,   // (256,128,3)
    const float* __restrict__ W,     // (16,8,5)
    float* __restrict__ ws)          // (2048,) per-block sums
{
    __shared__ float x[LSZ * LSZ];     // 65536 B
    __shared__ float nsm[LSZ * 3];     // 1536 B
    __shared__ float wsm[NLAY * 5];    // 320 B
    __shared__ float red[8];

    const int bid = blockIdx.x;
    const int b   = bid >> 3;
    const int c   = bid & 7;
    const int tid = threadIdx.x;

    // stage n[b] and this channel's 16x5 weights
    if (tid < LSZ * 3) nsm[tid] = nrm[b * (LSZ * 3) + tid];
    if (tid < NLAY * 5) {
        int l = tid / 5, d = tid % 5;
        wsm[tid] = W[l * (NCH * 5) + c * 5 + d];
    }
    __syncthreads();

    const int jg = tid & 31;        // col group
    const int is = tid >> 5;        // row strip
    const int j0 = jg * 4;
    const int i0 = is * 8;

    // ---- init: g[i][j] = dot3(n[i], n[j]), zero diagonal ----
    float nj[4][3];
#pragma unroll
    for (int q = 0; q < 4; ++q)
#pragma unroll
        for (int a = 0; a < 3; ++a)
            nj[q][a] = nsm[(j0 + q) * 3 + a];

#pragma unroll
    for (int k = 0; k < 8; ++k) {
        int r = i0 + k;
        float n0 = nsm[r * 3 + 0], n1 = nsm[r * 3 + 1], n2 = nsm[r * 3 + 2];
        float4 v;
        float g0 = n0 * nj[0][0] + n1 * nj[0][1] + n2 * nj[0][2];
        float g1 = n0 * nj[1][0] + n1 * nj[1][1] + n2 * nj[1][2];
        float g2 = n0 * nj[2][0] + n1 * nj[2][1] + n2 * nj[2][2];
        float g3 = n0 * nj[3][0] + n1 * nj[3][1] + n2 * nj[3][2];
        if (r == j0 + 0) g0 = 0.f;
        if (r == j0 + 1) g1 = 0.f;
        if (r == j0 + 2) g2 = 0.f;
        if (r == j0 + 3) g3 = 0.f;
        v.x = g0; v.y = g1; v.z = g2; v.w = g3;
        *(float4*)&x[r * LSZ + j0] = v;
    }
    __syncthreads();

    float cr[16][4];   // column cache: rows i0-4 .. i0+11 (wrapped); lower 8 reused as output stash

#pragma unroll 1
    for (int l = 0; l < NLAY; ++l) {
        const float w0 = wsm[l * 5 + 0];
        const float w1 = wsm[l * 5 + 1];
        const float w2 = wsm[l * 5 + 2];
        const float w3 = wsm[l * 5 + 3];
        const float w4 = wsm[l * 5 + 4];

#pragma unroll
        for (int k = 0; k < 16; ++k) {
            int r = (i0 + k - 4) & (LSZ - 1);
            float4 t = *(const float4*)&x[r * LSZ + j0];
            cr[k][0] = t.x; cr[k][1] = t.y; cr[k][2] = t.z; cr[k][3] = t.w;
        }

#pragma unroll
        for (int m = 0; m < 8; ++m) {
            int r = i0 + m;
            float4 hl4 = *(const float4*)&x[r * LSZ + ((j0 - 4) & (LSZ - 1))];
            float4 hr4 = *(const float4*)&x[r * LSZ + ((j0 + 4) & (LSZ - 1))];
            float win[12];
            win[0] = hl4.x; win[1] = hl4.y; win[2]  = hl4.z; win[3]  = hl4.w;
            win[4] = cr[m + 4][0]; win[5] = cr[m + 4][1];
            win[6] = cr[m + 4][2]; win[7] = cr[m + 4][3];
            win[8] = hr4.x; win[9] = hr4.y; win[10] = hr4.z; win[11] = hr4.w;
#pragma unroll
            for (int q = 0; q < 4; ++q) {
                float y = w0 * win[4 + q];
                y += w1 * (win[3 + q] + win[5 + q]);
                y += w2 * (win[2 + q] + win[6 + q]);
                y += w3 * (win[1 + q] + win[7 + q]);
                y += w4 * (win[0 + q] + win[8 + q]);
                y += w1 * (cr[m + 3][q] + cr[m + 5][q]);
                y += w2 * (cr[m + 2][q] + cr[m + 6][q]);
                y += w3 * (cr[m + 1][q] + cr[m + 7][q]);
                y += w4 * (cr[m + 0][q] + cr[m + 8][q]);
                float cel = fmaxf(y, 0.f) + expm1f(fminf(y, 0.f));
                cr[m][q] = cr[m + 4][q] + cel;   // cr[m] dead after this m -> stash result
            }
        }
        __syncthreads();
#pragma unroll
        for (int m = 0; m < 8; ++m) {
            float4 v;
            v.x = cr[m][0]; v.y = cr[m][1]; v.z = cr[m][2]; v.w = cr[m][3];
            *(float4*)&x[(i0 + m) * LSZ + j0] = v;
        }
        __syncthreads();
    }

    // ---- per-block sum of final plane (results live in cr[0..7]) ----
    float local = 0.f;
#pragma unroll
    for (int m = 0; m < 8; ++m)
#pragma unroll
        for (int q = 0; q < 4; ++q) local += cr[m][q];

#pragma unroll
    for (int off = 32; off > 0; off >>= 1)
        local += __shfl_down(local, off, 64);

    const int wave = tid >> 6;
    if ((tid & 63) == 0) red[wave] = local;
    __syncthreads();
    if (tid == 0) {
        float s = 0.f;
#pragma unroll
        for (int w = 0; w < 8; ++w) s += red[w];
        ws[bid] = s;
    }
}

__global__ void finish_kernel(const float* __restrict__ ws, float* __restrict__ out) {
    int b = threadIdx.x;
    float s = 0.f;
#pragma unroll
    for (int c = 0; c < NCH; ++c) s += ws[b * NCH + c];
    out[b] = expf(-s / (8.0f * 128.0f * 128.0f));
}

extern "C" void kernel_launch(void* const* d_in, const int* in_sizes, int n_in,
                              void* d_out, int out_size, void* d_ws, size_t ws_size,
                              hipStream_t stream) {
    const float* nrm = (const float*)d_in[0];   // (256,128,3) f32
    const float* W   = (const float*)d_in[1];   // (16,8,5) f32
    float* out = (float*)d_out;                 // (256,) f32
    float* ws  = (float*)d_ws;                  // >= 2048 f32 scratch

    plane_kernel<<<dim3(256 * NCH), dim3(512), 0, stream>>>(nrm, W, ws);
    finish_kernel<<<dim3(1), dim3(256), 0, stream>>>(ws, out);
}

// Round 2
// 725.968 us; speedup vs baseline: 2.4392x; 2.4392x over previous
//
#include <hip/hip_runtime.h>
#include <math.h>

#define LSZ 128
#define NCH 8
#define NLAY 16

__device__ __forceinline__ float4 f4add(float4 a, float4 b) {
    return make_float4(a.x + b.x, a.y + b.y, a.z + b.z, a.w + b.w);
}
__device__ __forceinline__ float4 f4fma(float s, float4 a, float4 acc) {
    return make_float4(fmaf(s, a.x, acc.x), fmaf(s, a.y, acc.y),
                       fmaf(s, a.z, acc.z), fmaf(s, a.w, acc.w));
}
__device__ __forceinline__ float4 f4scale(float s, float4 a) {
    return make_float4(s * a.x, s * a.y, s * a.z, s * a.w);
}
__device__ __forceinline__ float celu1(float y) {
    return fmaxf(y, 0.f) + expm1f(fminf(y, 0.f));
}

// One block per (batch, channel) plane. 512 threads: 16 row-strips x 32 col-groups.
// Each thread owns 8 rows x 4 cols. Plane lives in LDS (64 KB), updated in place.
// All per-thread state is float4 scalars / small 1-D float4 arrays with
// compile-time indices only -> must stay in VGPRs (no scratch).
__global__ __launch_bounds__(512)
__attribute__((amdgpu_waves_per_eu(2, 4)))
void plane_kernel(const float* __restrict__ nrm,   // (256,128,3)
                  const float* __restrict__ W,     // (16,8,5)
                  float* __restrict__ ws)          // (2048,) per-block sums
{
    __shared__ float x[LSZ * LSZ];     // 65536 B
    __shared__ float nsm[LSZ * 3];     // 1536 B
    __shared__ float wsm[NLAY * 5];    // 320 B
    __shared__ float red[8];

    const int bid = blockIdx.x;
    const int b   = bid >> 3;
    const int c   = bid & 7;
    const int tid = threadIdx.x;

    if (tid < LSZ * 3) nsm[tid] = nrm[b * (LSZ * 3) + tid];
    if (tid < NLAY * 5) {
        int l = tid / 5, d = tid % 5;
        wsm[tid] = W[l * (NCH * 5) + c * 5 + d];
    }
    __syncthreads();

    const int jg = tid & 31;        // col group
    const int is = tid >> 5;        // row strip
    const int j0 = jg * 4;
    const int i0 = is * 8;

    // ---- init: g[i][j] = dot3(n[i], n[j]), zero diagonal ----
    {
        float nj0x = nsm[(j0 + 0) * 3 + 0], nj0y = nsm[(j0 + 0) * 3 + 1], nj0z = nsm[(j0 + 0) * 3 + 2];
        float nj1x = nsm[(j0 + 1) * 3 + 0], nj1y = nsm[(j0 + 1) * 3 + 1], nj1z = nsm[(j0 + 1) * 3 + 2];
        float nj2x = nsm[(j0 + 2) * 3 + 0], nj2y = nsm[(j0 + 2) * 3 + 1], nj2z = nsm[(j0 + 2) * 3 + 2];
        float nj3x = nsm[(j0 + 3) * 3 + 0], nj3y = nsm[(j0 + 3) * 3 + 1], nj3z = nsm[(j0 + 3) * 3 + 2];
#pragma unroll
        for (int k = 0; k < 8; ++k) {
            int r = i0 + k;
            float n0 = nsm[r * 3 + 0], n1 = nsm[r * 3 + 1], n2 = nsm[r * 3 + 2];
            float g0 = n0 * nj0x + n1 * nj0y + n2 * nj0z;
            float g1 = n0 * nj1x + n1 * nj1y + n2 * nj1z;
            float g2 = n0 * nj2x + n1 * nj2y + n2 * nj2z;
            float g3 = n0 * nj3x + n1 * nj3y + n2 * nj3z;
            if (r == j0 + 0) g0 = 0.f;
            if (r == j0 + 1) g1 = 0.f;
            if (r == j0 + 2) g2 = 0.f;
            if (r == j0 + 3) g3 = 0.f;
            *(float4*)&x[r * LSZ + j0] = make_float4(g0, g1, g2, g3);
        }
    }
    __syncthreads();

    // column cache: rows i0-4 .. i0+11 (wrapped); cr[m] is dead after
    // iteration m and is reused as the output stash for row i0+m.
    float4 cr[16];

    const int jl = (j0 - 4) & (LSZ - 1);
    const int jr = (j0 + 4) & (LSZ - 1);

#pragma unroll 1
    for (int l = 0; l < NLAY; ++l) {
        const float w0 = wsm[l * 5 + 0];
        const float w1 = wsm[l * 5 + 1];
        const float w2 = wsm[l * 5 + 2];
        const float w3 = wsm[l * 5 + 3];
        const float w4 = wsm[l * 5 + 4];

#pragma unroll
        for (int k = 0; k < 16; ++k) {
            int r = (i0 + k - 4) & (LSZ - 1);
            cr[k] = *(const float4*)&x[r * LSZ + j0];
        }

#pragma unroll
        for (int m = 0; m < 8; ++m) {
            const int r = i0 + m;
            const float4 L = *(const float4*)&x[r * LSZ + jl];
            const float4 R = *(const float4*)&x[r * LSZ + jr];
            const float4 C = cr[m + 4];

            // horizontal shifted taps (j-d + j+d), d = 1..4
            float4 h1 = make_float4(L.w + C.y, C.x + C.z, C.y + C.w, C.z + R.x);
            float4 h2 = make_float4(L.z + C.z, L.w + C.w, C.x + R.x, C.y + R.y);
            float4 h3 = make_float4(L.y + C.w, L.z + R.x, L.w + R.y, C.x + R.z);
            float4 h4 = f4add(L, R);

            float4 y = f4scale(w0, C);
            y = f4fma(w1, f4add(h1, f4add(cr[m + 3], cr[m + 5])), y);
            y = f4fma(w2, f4add(h2, f4add(cr[m + 2], cr[m + 6])), y);
            y = f4fma(w3, f4add(h3, f4add(cr[m + 1], cr[m + 7])), y);
            y = f4fma(w4, f4add(h4, f4add(cr[m + 0], cr[m + 8])), y);

            float4 res;
            res.x = C.x + celu1(y.x);
            res.y = C.y + celu1(y.y);
            res.z = C.z + celu1(y.z);
            res.w = C.w + celu1(y.w);
            cr[m] = res;                       // stash (cr[m] dead after this m)
        }
        __syncthreads();
#pragma unroll
        for (int m = 0; m < 8; ++m)
            *(float4*)&x[(i0 + m) * LSZ + j0] = cr[m];
        __syncthreads();
    }

    // ---- per-block sum of final plane (results live in cr[0..7]) ----
    float local = 0.f;
#pragma unroll
    for (int m = 0; m < 8; ++m)
        local += cr[m].x + cr[m].y + cr[m].z + cr[m].w;

#pragma unroll
    for (int off = 32; off > 0; off >>= 1)
        local += __shfl_down(local, off, 64);

    const int wave = tid >> 6;
    if ((tid & 63) == 0) red[wave] = local;
    __syncthreads();
    if (tid == 0) {
        float s = 0.f;
#pragma unroll
        for (int w = 0; w < 8; ++w) s += red[w];
        ws[bid] = s;
    }
}

__global__ void finish_kernel(const float* __restrict__ ws, float* __restrict__ out) {
    int b = threadIdx.x;
    float s = 0.f;
#pragma unroll
    for (int c = 0; c < NCH; ++c) s += ws[b * NCH + c];
    out[b] = expf(-s / (8.0f * 128.0f * 128.0f));
}

extern "C" void kernel_launch(void* const* d_in, const int* in_sizes, int n_in,
                              void* d_out, int out_size, void* d_ws, size_t ws_size,
                              hipStream_t stream) {
    const float* nrm = (const float*)d_in[0];   // (256,128,3) f32
    const float* W   = (const float*)d_in[1];   // (16,8,5) f32
    float* out = (float*)d_out;                 // (256,) f32
    float* ws  = (float*)d_ws;                  // >= 2048 f32 scratch

    plane_kernel<<<dim3(256 * NCH), dim3(512), 0, stream>>>(nrm, W, ws);
    finish_kernel<<<dim3(1), dim3(256), 0, stream>>>(ws, out);
}

// Round 3
// 497.559 us; speedup vs baseline: 3.5589x; 1.4591x over previous
//
#include <hip/hip_runtime.h>
#include <math.h>

#define LSZ 128
#define NCH 8
#define NLAY 16

__device__ __forceinline__ float4 f4add(float4 a, float4 b) {
    return make_float4(a.x + b.x, a.y + b.y, a.z + b.z, a.w + b.w);
}
__device__ __forceinline__ float4 f4fma(float s, float4 a, float4 acc) {
    return make_float4(fmaf(s, a.x, acc.x), fmaf(s, a.y, acc.y),
                       fmaf(s, a.z, acc.z), fmaf(s, a.w, acc.w));
}
__device__ __forceinline__ float4 f4scale(float s, float4 a) {
    return make_float4(s * a.x, s * a.y, s * a.z, s * a.w);
}
// CELU(y) = max(y,0) + exp(min(y,0)) - 1.  exp(0)==1 exactly, so the y>=0
// branch contributes exactly 0.  __expf -> v_mul + v_exp_f32 (trans pipe).
__device__ __forceinline__ float celu1(float y) {
    return fmaxf(y, 0.f) + (__expf(fminf(y, 0.f)) - 1.f);
}

// One block per (batch, channel) plane. 512 threads: 16 row-strips x 32 col-groups.
// Each thread owns 8 rows x 4 cols. Plane lives in LDS (64 KB), updated in place.
// Own rows are carried in registers across layers (cr[4..11]); only the 8 halo
// rows + 16 horizontal halo vectors are re-read from LDS each layer.
__global__ __launch_bounds__(512)
__attribute__((amdgpu_waves_per_eu(2, 4)))
void plane_kernel(const float* __restrict__ nrm,   // (256,128,3)
                  const float* __restrict__ W,     // (16,8,5)
                  float* __restrict__ ws)          // (2048,) per-block sums
{
    __shared__ float x[LSZ * LSZ];     // 65536 B
    __shared__ float nsm[LSZ * 3];     // 1536 B
    __shared__ float wsm[NLAY * 5];    // 320 B
    __shared__ float red[8];

    const int bid = blockIdx.x;
    const int b   = bid >> 3;
    const int c   = bid & 7;
    const int tid = threadIdx.x;

    if (tid < LSZ * 3) nsm[tid] = nrm[b * (LSZ * 3) + tid];
    if (tid < NLAY * 5) {
        int l = tid / 5, d = tid % 5;
        wsm[tid] = W[l * (NCH * 5) + c * 5 + d];
    }
    __syncthreads();

    const int jg = tid & 31;        // col group
    const int is = tid >> 5;        // row strip
    const int j0 = jg * 4;
    const int i0 = is * 8;

    // column cache, rows i0-4 .. i0+11 (wrapped). cr[4..11] = own rows,
    // carried in registers across layers. cr[m] (halo, dead after use at
    // iteration m) doubles as the output stash for row i0+m.
    float4 cr[16];

    // ---- init: g[i][j] = dot3(n[i], n[j]), zero diagonal ----
    {
        float nj0x = nsm[(j0 + 0) * 3 + 0], nj0y = nsm[(j0 + 0) * 3 + 1], nj0z = nsm[(j0 + 0) * 3 + 2];
        float nj1x = nsm[(j0 + 1) * 3 + 0], nj1y = nsm[(j0 + 1) * 3 + 1], nj1z = nsm[(j0 + 1) * 3 + 2];
        float nj2x = nsm[(j0 + 2) * 3 + 0], nj2y = nsm[(j0 + 2) * 3 + 1], nj2z = nsm[(j0 + 2) * 3 + 2];
        float nj3x = nsm[(j0 + 3) * 3 + 0], nj3y = nsm[(j0 + 3) * 3 + 1], nj3z = nsm[(j0 + 3) * 3 + 2];
#pragma unroll
        for (int k = 0; k < 8; ++k) {
            int r = i0 + k;
            float n0 = nsm[r * 3 + 0], n1 = nsm[r * 3 + 1], n2 = nsm[r * 3 + 2];
            float g0 = n0 * nj0x + n1 * nj0y + n2 * nj0z;
            float g1 = n0 * nj1x + n1 * nj1y + n2 * nj1z;
            float g2 = n0 * nj2x + n1 * nj2y + n2 * nj2z;
            float g3 = n0 * nj3x + n1 * nj3y + n2 * nj3z;
            if (r == j0 + 0) g0 = 0.f;
            if (r == j0 + 1) g1 = 0.f;
            if (r == j0 + 2) g2 = 0.f;
            if (r == j0 + 3) g3 = 0.f;
            float4 v = make_float4(g0, g1, g2, g3);
            *(float4*)&x[r * LSZ + j0] = v;
            cr[4 + k] = v;                 // own rows start in registers
        }
    }
    __syncthreads();

    const int jl = (j0 - 4) & (LSZ - 1);
    const int jr = (j0 + 4) & (LSZ - 1);

#pragma unroll 1
    for (int l = 0; l < NLAY; ++l) {
        const float w0 = wsm[l * 5 + 0];
        const float w1 = wsm[l * 5 + 1];
        const float w2 = wsm[l * 5 + 2];
        const float w3 = wsm[l * 5 + 3];
        const float w4 = wsm[l * 5 + 4];

        // halo rows only (own rows already live in cr[4..11])
#pragma unroll
        for (int k = 0; k < 4; ++k) {
            int rt = (i0 + k - 4) & (LSZ - 1);
            cr[k] = *(const float4*)&x[rt * LSZ + j0];
            int rb = (i0 + 8 + k) & (LSZ - 1);
            cr[12 + k] = *(const float4*)&x[rb * LSZ + j0];
        }

#pragma unroll
        for (int m = 0; m < 8; ++m) {
            const int r = i0 + m;
            const float4 L = *(const float4*)&x[r * LSZ + jl];
            const float4 R = *(const float4*)&x[r * LSZ + jr];
            const float4 C = cr[m + 4];

            // horizontal shifted taps (j-d + j+d), d = 1..4
            float4 h1 = make_float4(L.w + C.y, C.x + C.z, C.y + C.w, C.z + R.x);
            float4 h2 = make_float4(L.z + C.z, L.w + C.w, C.x + R.x, C.y + R.y);
            float4 h3 = make_float4(L.y + C.w, L.z + R.x, L.w + R.y, C.x + R.z);
            float4 h4 = f4add(L, R);

            float4 y = f4scale(w0, C);
            y = f4fma(w1, f4add(h1, f4add(cr[m + 3], cr[m + 5])), y);
            y = f4fma(w2, f4add(h2, f4add(cr[m + 2], cr[m + 6])), y);
            y = f4fma(w3, f4add(h3, f4add(cr[m + 1], cr[m + 7])), y);
            y = f4fma(w4, f4add(h4, f4add(cr[m + 0], cr[m + 8])), y);

            float4 res;
            res.x = C.x + celu1(y.x);
            res.y = C.y + celu1(y.y);
            res.z = C.z + celu1(y.z);
            res.w = C.w + celu1(y.w);
            cr[m] = res;                       // stash (cr[m] dead after this m)
        }
        __syncthreads();
#pragma unroll
        for (int m = 0; m < 8; ++m)
            *(float4*)&x[(i0 + m) * LSZ + j0] = cr[m];
        __syncthreads();

        // carry results into the own-row slots for the next layer
#pragma unroll
        for (int k = 7; k >= 0; --k)
            cr[4 + k] = cr[k];
    }

    // ---- per-block sum of final plane (results live in cr[4..11]) ----
    float local = 0.f;
#pragma unroll
    for (int m = 4; m < 12; ++m)
        local += cr[m].x + cr[m].y + cr[m].z + cr[m].w;

#pragma unroll
    for (int off = 32; off > 0; off >>= 1)
        local += __shfl_down(local, off, 64);

    const int wave = tid >> 6;
    if ((tid & 63) == 0) red[wave] = local;
    __syncthreads();
    if (tid == 0) {
        float s = 0.f;
#pragma unroll
        for (int w = 0; w < 8; ++w) s += red[w];
        ws[bid] = s;
    }
}

__global__ void finish_kernel(const float* __restrict__ ws, float* __restrict__ out) {
    int b = threadIdx.x;
    float s = 0.f;
#pragma unroll
    for (int c = 0; c < NCH; ++c) s += ws[b * NCH + c];
    out[b] = expf(-s / (8.0f * 128.0f * 128.0f));
}

extern "C" void kernel_launch(void* const* d_in, const int* in_sizes, int n_in,
                              void* d_out, int out_size, void* d_ws, size_t ws_size,
                              hipStream_t stream) {
    const float* nrm = (const float*)d_in[0];   // (256,128,3) f32
    const float* W   = (const float*)d_in[1];   // (16,8,5) f32
    float* out = (float*)d_out;                 // (256,) f32
    float* ws  = (float*)d_ws;                  // >= 2048 f32 scratch

    plane_kernel<<<dim3(256 * NCH), dim3(512), 0, stream>>>(nrm, W, ws);
    finish_kernel<<<dim3(1), dim3(256), 0, stream>>>(ws, out);
}